// Round 3
// baseline (331.586 us; speedup 1.0000x reference)
//
#include <hip/hip_runtime.h>
#include <hip/hip_bf16.h>

#define A_N   2048
#define D_N   64
#define FL_N  12
#define KTOT  (A_N * FL_N)          // 24576
#define S_SPLIT 32
#define KCHUNK (KTOT / S_SPLIT)     // 768

typedef __attribute__((ext_vector_type(8))) short bf16x8;  // 8 bf16 = 4 VGPRs
typedef __attribute__((ext_vector_type(4))) short bf16x4;  // 8 B
typedef __attribute__((ext_vector_type(4))) float f32x4;

__device__ __forceinline__ short f2bf(float f) {
  union { __hip_bfloat16 b; short s; } u;
  u.b = __float2bfloat16(f);
  return u.s;
}

// ---------- fused one-time setup ----------
// blocks [0,192): P2_i[o][f][d] = pf_i[o,f,d]*bf_i[o,f,0]
// blocks [192,704): bond_i[a][o] = sum_f bp[a,f,0]*bf_i[o,f,1]+bp[a,f,1]*bf_i[o,f,2]
// blocks [704,768): xb = bf16(x)
__global__ void k_setup(const float* __restrict__ pf0, const float* __restrict__ bf0,
                        const float* __restrict__ pf1, const float* __restrict__ bf1,
                        const float* __restrict__ bp, const float* __restrict__ x,
                        short* __restrict__ P2_0, short* __restrict__ P2_1,
                        float* __restrict__ bond0, float* __restrict__ bond1,
                        short* __restrict__ xb) {
  int b = blockIdx.x, t = threadIdx.x;
  if (b < 192) {
    int idx = b * 256 + t;                       // < 49152
    int f = (idx >> 6) % FL_N;
    int o = idx / (D_N * FL_N);
    P2_0[idx] = f2bf(pf0[idx] * bf0[(o * FL_N + f) * 3]);
    P2_1[idx] = f2bf(pf1[idx] * bf1[(o * FL_N + f) * 3]);
  } else if (b < 704) {
    int o = t & 63;
    int a = (b - 192) * 4 + (t >> 6);
    float s0 = 0.f, s1 = 0.f;
#pragma unroll
    for (int f = 0; f < FL_N; ++f) {
      float c0 = bp[(a * FL_N + f) * 2 + 0];
      float c1 = bp[(a * FL_N + f) * 2 + 1];
      s0 += c0 * bf0[(o * FL_N + f) * 3 + 1] + c1 * bf0[(o * FL_N + f) * 3 + 2];
      s1 += c0 * bf1[(o * FL_N + f) * 3 + 1] + c1 * bf1[(o * FL_N + f) * 3 + 2];
    }
    bond0[a * D_N + o] = s0;
    bond1[a * D_N + o] = s1;
  } else {
    int i = ((b - 704) * 256 + t) * 8;
    f32x4 a0 = *(const f32x4*)(x + i);
    f32x4 a1 = *(const f32x4*)(x + i + 4);
    bf16x8 v;
    v[0]=f2bf(a0[0]); v[1]=f2bf(a0[1]); v[2]=f2bf(a0[2]); v[3]=f2bf(a0[3]);
    v[4]=f2bf(a1[0]); v[5]=f2bf(a1[1]); v[6]=f2bf(a1[2]); v[7]=f2bf(a1[3]);
    *(bf16x8*)(xb + i) = v;
  }
}

// ---------- Bt prep (shared MFMA body) ----------
// Bt[o][k*FL+f] = sum_d h[k,d] * P2[o,f,d];  16x16x32: M=o(16/wave), N=k(16/block), K=d(64)
__device__ __forceinline__ void prep_body(bf16x8 h0, bf16x8 h1,
                                          const short* __restrict__ P2,
                                          short* __restrict__ Bt,
                                          int k0, int lane, int w) {
  int l15 = lane & 15, grp = lane >> 4;
  const short* prow = P2 + (w * 16 + l15) * (FL_N * D_N) + grp * 8;
  f32x4 acc[FL_N];
#pragma unroll
  for (int f = 0; f < FL_N; ++f) {
    bf16x8 p0 = *(const bf16x8*)(prow + f * D_N);
    bf16x8 p1 = *(const bf16x8*)(prow + f * D_N + 32);
    f32x4 c = {0.f, 0.f, 0.f, 0.f};
    c = __builtin_amdgcn_mfma_f32_16x16x32_bf16(p0, h0, c, 0, 0, 0);
    c = __builtin_amdgcn_mfma_f32_16x16x32_bf16(p1, h1, c, 0, 0, 0);
    acc[f] = c;
  }
  // D layout: row(o) = grp*4 + r (+w*16), col(k) = l15 (+k0)
#pragma unroll
  for (int r = 0; r < 4; ++r) {
    int o = w * 16 + grp * 4 + r;
    int k = k0 + l15;
    short ov[FL_N];
#pragma unroll
    for (int f = 0; f < FL_N; ++f) ov[f] = f2bf(acc[f][r]);
    short* dst = Bt + (size_t)o * KTOT + (size_t)k * FL_N;
    *(bf16x4*)(dst)     = *(const bf16x4*)(ov);
    *(bf16x4*)(dst + 4) = *(const bf16x4*)(ov + 4);
    *(bf16x4*)(dst + 8) = *(const bf16x4*)(ov + 8);
  }
}

// prep for conv0: h comes straight from xb
__global__ void k_prep0(const short* __restrict__ xb, const short* __restrict__ P2,
                        short* __restrict__ Bt) {
  int lane = threadIdx.x & 63, w = threadIdx.x >> 6;
  int l15 = lane & 15, grp = lane >> 4;
  int k0 = blockIdx.x * 16;
  const short* hrow = xb + (k0 + l15) * D_N + grp * 8;
  bf16x8 h0 = *(const bf16x8*)(hrow);
  bf16x8 h1 = *(const bf16x8*)(hrow + 32);
  prep_body(h0, h1, P2, Bt, k0, lane, w);
}

// prep for conv c (c>0): reduce previous conv's partials for this block's 16 rows,
// apply bond (+x) + relu, stage h tile in LDS, then MFMA-prep Bt.
template <int ADDX>
__global__ void k_prep_r(const float* __restrict__ part, const float* __restrict__ bond,
                         const float* __restrict__ x, const short* __restrict__ P2,
                         short* __restrict__ Bt) {
  __shared__ short hsh[16 * 64];
  int t = threadIdx.x;
  int k0 = blockIdx.x * 16;
  int r  = t >> 4;            // 0..15 local row
  int d0 = (t & 15) * 4;      // 4 floats per thread
  size_t base = (size_t)(k0 + r) * D_N + d0;
  f32x4 s = *(const f32x4*)(bond + base);
#pragma unroll
  for (int si = 0; si < S_SPLIT; ++si) {
    f32x4 p = *(const f32x4*)(part + (size_t)si * (A_N * D_N) + base);
    s[0] += p[0]; s[1] += p[1]; s[2] += p[2]; s[3] += p[3];
  }
  if (ADDX) {
    f32x4 xv = *(const f32x4*)(x + base);
    s[0] += xv[0]; s[1] += xv[1]; s[2] += xv[2]; s[3] += xv[3];
  }
  bf16x4 hv;
  hv[0] = f2bf(fmaxf(s[0], 0.f)); hv[1] = f2bf(fmaxf(s[1], 0.f));
  hv[2] = f2bf(fmaxf(s[2], 0.f)); hv[3] = f2bf(fmaxf(s[3], 0.f));
  *(bf16x4*)(&hsh[r * 64 + d0]) = hv;
  __syncthreads();
  int lane = t & 63, w = t >> 6, l15 = lane & 15, grp = lane >> 4;
  bf16x8 h0 = *(const bf16x8*)(&hsh[l15 * 64 + grp * 8]);
  bf16x8 h1 = *(const bf16x8*)(&hsh[l15 * 64 + grp * 8 + 32]);
  prep_body(h0, h1, P2, Bt, k0, lane, w);
}

// ---------- big GEMM (software-pipelined) ----------
// part[kc][a][o] = sum_{j in chunk} conn[a][j] * Bt[o][j]
template <int CVT>
__device__ __forceinline__ void gemm_body(const float* __restrict__ conn,
                                          short* __restrict__ connb,
                                          const short* __restrict__ Bt,
                                          float* __restrict__ part) {
  int mt   = blockIdx.x;
  int kc   = blockIdx.y;
  int lane = threadIdx.x & 63;
  int w    = threadIdx.x >> 6;
  int l15  = lane & 15;
  int grp  = lane >> 4;

  int row = mt * 64 + w * 16 + l15;
  size_t abase = (size_t)row * KTOT + (size_t)kc * KCHUNK + grp * 8;
  const float* ap  = conn  + abase;
  const short* abp = connb + abase;
  short*       cwp = connb + abase;
  const short* bp  = Bt + (size_t)l15 * KTOT + (size_t)kc * KCHUNK + grp * 8;

  f32x4 acc0 = {0,0,0,0}, acc1 = {0,0,0,0}, acc2 = {0,0,0,0}, acc3 = {0,0,0,0};

  constexpr int NS = KCHUNK / 32;   // 24

  f32x4  a0p[2], a1p[2];   // CVT=1 pipeline regs (raw f32)
  bf16x8 abr[2];           // CVT=0 pipeline regs
  bf16x8 b0p[2], b1p[2], b2p[2], b3p[2];

  if (CVT) {
    a0p[0] = __builtin_nontemporal_load((const f32x4*)(ap));
    a1p[0] = __builtin_nontemporal_load((const f32x4*)(ap + 4));
  } else {
    abr[0] = *(const bf16x8*)(abp);
  }
  b0p[0] = *(const bf16x8*)(bp);
  b1p[0] = *(const bf16x8*)(bp + (size_t)16 * KTOT);
  b2p[0] = *(const bf16x8*)(bp + (size_t)32 * KTOT);
  b3p[0] = *(const bf16x8*)(bp + (size_t)48 * KTOT);

#pragma unroll
  for (int ks = 0; ks < NS; ++ks) {
    const int cur = ks & 1, nxt = cur ^ 1;
    if (ks + 1 < NS) {
      const size_t o = (size_t)(ks + 1) * 32;
      if (CVT) {
        a0p[nxt] = __builtin_nontemporal_load((const f32x4*)(ap + o));
        a1p[nxt] = __builtin_nontemporal_load((const f32x4*)(ap + o + 4));
      } else {
        abr[nxt] = *(const bf16x8*)(abp + o);
      }
      b0p[nxt] = *(const bf16x8*)(bp + o);
      b1p[nxt] = *(const bf16x8*)(bp + o + (size_t)16 * KTOT);
      b2p[nxt] = *(const bf16x8*)(bp + o + (size_t)32 * KTOT);
      b3p[nxt] = *(const bf16x8*)(bp + o + (size_t)48 * KTOT);
    }
    bf16x8 af;
    if (CVT) {
      af[0]=f2bf(a0p[cur][0]); af[1]=f2bf(a0p[cur][1]); af[2]=f2bf(a0p[cur][2]); af[3]=f2bf(a0p[cur][3]);
      af[4]=f2bf(a1p[cur][0]); af[5]=f2bf(a1p[cur][1]); af[6]=f2bf(a1p[cur][2]); af[7]=f2bf(a1p[cur][3]);
      *(bf16x8*)(cwp + (size_t)ks * 32) = af;   // persist bf16 copy (L3-resident)
    } else {
      af = abr[cur];
    }
    acc0 = __builtin_amdgcn_mfma_f32_16x16x32_bf16(af, b0p[cur], acc0, 0, 0, 0);
    acc1 = __builtin_amdgcn_mfma_f32_16x16x32_bf16(af, b1p[cur], acc1, 0, 0, 0);
    acc2 = __builtin_amdgcn_mfma_f32_16x16x32_bf16(af, b2p[cur], acc2, 0, 0, 0);
    acc3 = __builtin_amdgcn_mfma_f32_16x16x32_bf16(af, b3p[cur], acc3, 0, 0, 0);
  }

  float* p = part + (size_t)kc * (A_N * D_N);
  int ab = mt * 64 + w * 16 + grp * 4;
#pragma unroll
  for (int r = 0; r < 4; ++r) {
    float* pr = p + (size_t)(ab + r) * D_N + l15;
    pr[0]  = acc0[r];
    pr[16] = acc1[r];
    pr[32] = acc2[r];
    pr[48] = acc3[r];
  }
}

__global__ __launch_bounds__(256, 4) void k_gemm_cvt(const float* __restrict__ conn,
                                                     short* __restrict__ connb,
                                                     const short* __restrict__ Bt,
                                                     float* __restrict__ part) {
  gemm_body<1>(conn, connb, Bt, part);
}
__global__ __launch_bounds__(256, 4) void k_gemm_b16(const float* __restrict__ conn,
                                                     short* __restrict__ connb,
                                                     const short* __restrict__ Bt,
                                                     float* __restrict__ part) {
  gemm_body<0>(conn, connb, Bt, part);
}

// ---------- final reduce -> f32 out ----------
__global__ void k_final(const float* __restrict__ part, const float* __restrict__ bond,
                        const float* __restrict__ x, float* __restrict__ out) {
  int i = (blockIdx.x * 256 + threadIdx.x) * 4;   // 131072 total
  f32x4 s = *(const f32x4*)(bond + i);
#pragma unroll
  for (int si = 0; si < S_SPLIT; ++si) {
    f32x4 p = *(const f32x4*)(part + (size_t)si * (A_N * D_N) + i);
    s[0] += p[0]; s[1] += p[1]; s[2] += p[2]; s[3] += p[3];
  }
  f32x4 xv = *(const f32x4*)(x + i);
  f32x4 o;
  o[0] = fmaxf(s[0] + xv[0], 0.f); o[1] = fmaxf(s[1] + xv[1], 0.f);
  o[2] = fmaxf(s[2] + xv[2], 0.f); o[3] = fmaxf(s[3] + xv[3], 0.f);
  *(f32x4*)(out + i) = o;
}

// ---------- launch ----------
extern "C" void kernel_launch(void* const* d_in, const int* in_sizes, int n_in,
                              void* d_out, int out_size, void* d_ws, size_t ws_size,
                              hipStream_t stream) {
  const float* x    = (const float*)d_in[0];
  const float* conn = (const float*)d_in[1];
  const float* bprp = (const float*)d_in[2];
  const float* pf0  = (const float*)d_in[3];
  const float* bf0  = (const float*)d_in[4];
  const float* pf1  = (const float*)d_in[5];
  const float* bf1  = (const float*)d_in[6];
  float* out = (float*)d_out;

  char* ws = (char*)d_ws;
  size_t off = 0;
  short* connb = (short*)(ws + off); off += (size_t)A_N * KTOT * 2;           // 100.7 MB
  short* Bt    = (short*)(ws + off); off += (size_t)D_N * KTOT * 2;           // 3 MB
  float* part  = (float*)(ws + off); off += (size_t)S_SPLIT * A_N * D_N * 4;  // 16.8 MB
  short* xb    = (short*)(ws + off); off += (size_t)A_N * D_N * 2;
  float* bond0 = (float*)(ws + off); off += (size_t)A_N * D_N * 4;
  float* bond1 = (float*)(ws + off); off += (size_t)A_N * D_N * 4;
  short* P2_0  = (short*)(ws + off); off += (size_t)D_N * FL_N * D_N * 2;
  short* P2_1  = (short*)(ws + off); off += (size_t)D_N * FL_N * D_N * 2;

  k_setup<<<768, 256, 0, stream>>>(pf0, bf0, pf1, bf1, bprp, x,
                                   P2_0, P2_1, bond0, bond1, xb);

  dim3 ggrid(32, S_SPLIT);

  // conv0: h = x
  k_prep0<<<128, 256, 0, stream>>>(xb, P2_0, Bt);
  k_gemm_cvt<<<ggrid, 256, 0, stream>>>(conn, connb, Bt, part);

  // conv1: h1 = relu(conv0), no +x; bond0; P2_0
  k_prep_r<0><<<128, 256, 0, stream>>>(part, bond0, x, P2_0, Bt);
  k_gemm_b16<<<ggrid, 256, 0, stream>>>(conn, connb, Bt, part);

  // conv2: h2 = relu(conv1 + x); bond0; P2_1
  k_prep_r<1><<<128, 256, 0, stream>>>(part, bond0, x, P2_1, Bt);
  k_gemm_b16<<<ggrid, 256, 0, stream>>>(conn, connb, Bt, part);

  // conv3: h3 = relu(conv2), no +x; bond1; P2_1
  k_prep_r<0><<<128, 256, 0, stream>>>(part, bond1, x, P2_1, Bt);
  k_gemm_b16<<<ggrid, 256, 0, stream>>>(conn, connb, Bt, part);

  // out = relu(conv3 + x)
  k_final<<<128, 256, 0, stream>>>(part, bond1, x, out);
}